// Round 1
// baseline (311.020 us; speedup 1.0000x reference)
//
#include <hip/hip_runtime.h>
#include <math.h>

// ---------------------------------------------------------------------------
// Mamba_v3 fused block, fp32 baseline.
// Pipeline: K1 mods GEMM -> K2 shuffle+LN+mod -> K3 in_proj GEMM -> K4 conv+silu
//           -> K4b x_proj GEMM -> K5 selective scan -> K6 out_proj GEMM+residual
//           -> K6b LN+mod -> K7 fc1 GEMM+gelu -> K8 fc2 GEMM+residual+unshuffle
// ---------------------------------------------------------------------------

__device__ __forceinline__ float sigf(float x){ return 1.f/(1.f+__expf(-x)); }
__device__ __forceinline__ float geluf(float x){
  float x3 = x*x*x;
  return 0.5f*x*(1.f + tanhf(0.7978845608f*(x + 0.044715f*x3)));
}

// Generic GEMM: C[m][n] = sum_k A[m*lda+k] * W[n*K+k]  (+ epilogue)
// EPI: 0 = store, 1 = +bias, 2 = gelu(+bias), 3 = x0 + g_m*acc (out_proj),
//      4 = x1 + g_p*(acc+bias) scattered to output via inverse pixel shuffle.
template<int BM,int BN,int BK,int TM,int TN,int EPI>
__global__ __launch_bounds__(256) void gemm_atw(
    const float* __restrict__ A, int lda,
    const float* __restrict__ W, int K,
    const float* __restrict__ bias,
    float* __restrict__ C, int ldc,
    const float* __restrict__ aux0,   // x0 (EPI3) / x1 (EPI4), ld 256
    const float* __restrict__ mods,   // (512,1536)
    float* __restrict__ out4)         // final output (EPI4)
{
  __shared__ float As[BK][BM+4];
  __shared__ float Ws[BK][BN+4];
  const int tid = threadIdx.x;
  const int m0 = blockIdx.y*BM, n0 = blockIdx.x*BN;
  float acc[TM][TN];
#pragma unroll
  for (int i=0;i<TM;i++)
#pragma unroll
    for (int j=0;j<TN;j++) acc[i][j]=0.f;

  for (int k0=0;k0<K;k0+=BK){
    for (int i=tid*4;i<BM*BK;i+=1024){
      int m=i/BK, k=i%BK;
      float4 v=*(const float4*)&A[(size_t)(m0+m)*lda+k0+k];
      As[k][m]=v.x; As[k+1][m]=v.y; As[k+2][m]=v.z; As[k+3][m]=v.w;
    }
    for (int i=tid*4;i<BN*BK;i+=1024){
      int n=i/BK, k=i%BK;
      float4 v=*(const float4*)&W[(size_t)(n0+n)*K+k0+k];
      Ws[k][n]=v.x; Ws[k+1][n]=v.y; Ws[k+2][n]=v.z; Ws[k+3][n]=v.w;
    }
    __syncthreads();
    const int tx=tid&15, ty=tid>>4;
#pragma unroll
    for (int k=0;k<BK;k++){
      float a[TM], bb[TN];
      float4 a4=*(const float4*)&As[k][ty*4];
      a[0]=a4.x;a[1]=a4.y;a[2]=a4.z;a[3]=a4.w;
      if constexpr (TN==4){
        float4 b4=*(const float4*)&Ws[k][tx*4];
        bb[0]=b4.x;bb[1]=b4.y;bb[2]=b4.z;bb[3]=b4.w;
      } else {
#pragma unroll
        for (int t=0;t<TN;t++) bb[t]=Ws[k][tx*TN+t];
      }
#pragma unroll
      for (int i=0;i<TM;i++)
#pragma unroll
        for (int j=0;j<TN;j++) acc[i][j] = fmaf(a[i], bb[j], acc[i][j]);
    }
    __syncthreads();
  }

  const int tx=tid&15, ty=tid>>4;
#pragma unroll
  for (int i=0;i<TM;i++){
    const int m=m0+ty*TM+i;
    const int b=m>>4;
    float v[TN];
#pragma unroll
    for (int j=0;j<TN;j++){
      const int n=n0+tx*TN+j;
      float x=acc[i][j];
      if constexpr (EPI==1) x += bias[n];
      if constexpr (EPI==2) x = geluf(x + bias[n]);
      if constexpr (EPI==3) x = aux0[(size_t)m*256+n] + mods[(size_t)b*1536+512+n]*x;
      if constexpr (EPI==4){
        x = aux0[(size_t)m*256+n] + mods[(size_t)b*1536+1280+n]*(x + bias[n]);
        const int pos=m&15;
        const int c=n>>6, hr=(n>>3)&7, wr=n&7;
        const int hh=(pos>>2)*8+hr, ww=(pos&3)*8+wr;
        out4[(((size_t)b*4+c)*32+hh)*32+ww] = x;
      }
      v[j]=x;
    }
    if constexpr (EPI!=4){
      if constexpr (TN==4){
        *(float4*)&C[(size_t)m*ldc+n0+tx*4] = make_float4(v[0],v[1],v[2],v[3]);
      } else {
#pragma unroll
        for (int j=0;j<TN;j++) C[(size_t)m*ldc+n0+tx*TN+j]=v[j];
      }
    }
  }
}

// LayerNorm + modulate. SHUF: gather from F_content via pixel shuffle and also
// write x0. One wave (64 lanes) per row of 256, 4 rows per block.
template<bool SHUF>
__global__ __launch_bounds__(256) void ln_mod(
    const float* __restrict__ src, const float* __restrict__ mods,
    int sh_off, float* __restrict__ x0_out, float* __restrict__ u_out)
{
  const int wave = threadIdx.x>>6, lane = threadIdx.x&63;
  const int m = blockIdx.x*4 + wave;       // 0..8191
  const int b = m>>4;
  const int c0 = lane*4;
  float4 v;
  if constexpr (SHUF){
    const int pos=m&15, hb=pos>>2, wb=pos&3;
    const int c=c0>>6, hr=(c0>>3)&7, wrb=c0&7;   // wrb in {0,4}
    v = *(const float4*)&src[(((size_t)b*4+c)*32 + hb*8+hr)*32 + wb*8 + wrb];
  } else {
    v = *(const float4*)&src[(size_t)m*256 + c0];
  }
  float s  = v.x+v.y+v.z+v.w;
  float s2 = v.x*v.x+v.y*v.y+v.z*v.z+v.w*v.w;
#pragma unroll
  for (int off=1; off<64; off<<=1){
    s  += __shfl_xor(s, off);
    s2 += __shfl_xor(s2, off);
  }
  const float mean = s*(1.f/256.f);
  const float var  = s2*(1.f/256.f) - mean*mean;
  const float rs   = rsqrtf(var + 1e-6f);
  float4 sh = *(const float4*)&mods[(size_t)b*1536 + sh_off + c0];
  float4 sc = *(const float4*)&mods[(size_t)b*1536 + sh_off + 256 + c0];
  float4 u;
  u.x = (v.x-mean)*rs*(1.f+sc.x) + sh.x;
  u.y = (v.y-mean)*rs*(1.f+sc.y) + sh.y;
  u.z = (v.z-mean)*rs*(1.f+sc.z) + sh.z;
  u.w = (v.w-mean)*rs*(1.f+sc.w) + sh.w;
  if constexpr (SHUF) *(float4*)&x0_out[(size_t)m*256+c0] = v;
  *(float4*)&u_out[(size_t)m*256+c0] = u;
}

// Depthwise causal conv (kernel 4) + SiLU. One thread per (b, d).
__global__ __launch_bounds__(256) void conv_silu(
    const float* __restrict__ xz, const float* __restrict__ cw,
    const float* __restrict__ cb, float* __restrict__ xs)
{
  const int t = blockIdx.x*256 + threadIdx.x;   // 0..262143
  const int b = t>>9, d = t&511;
  const float* xp = xz + (size_t)b*16384 + d;
  float x[16];
#pragma unroll
  for (int l=0;l<16;l++) x[l] = xp[(size_t)l*1024];
  const float w0=cw[d*4+0], w1=cw[d*4+1], w2=cw[d*4+2], w3=cw[d*4+3];
  const float bias = cb[d];
  float* op = xs + (size_t)b*8192 + d;
#pragma unroll
  for (int l=0;l<16;l++){
    float a = bias + w3*x[l];
    if (l>=1) a += w2*x[l-1];
    if (l>=2) a += w1*x[l-2];
    if (l>=3) a += w0*x[l-3];
    a = a*sigf(a);
    op[(size_t)l*512] = a;
  }
}

// Selective scan. One block per batch b (512 threads = channels d).
// delta recomputed on the fly from dt (in dbl) and dt_proj row d.
// y is written into the x-half of xz (dead after conv), gated by silu(z).
__global__ __launch_bounds__(512) void scan_kernel(
    const float* __restrict__ xs, float* __restrict__ xz,
    const float* __restrict__ dbl, const float* __restrict__ dtw,
    const float* __restrict__ dtb, const float* __restrict__ A_log,
    const float* __restrict__ Dskip)
{
  const int b = blockIdx.x, d = threadIdx.x;
  __shared__ float sdbl[768];                 // (16, 48): dt | B | C
  for (int i=d;i<768;i+=512) sdbl[i] = dbl[(size_t)b*768 + i];
  __syncthreads();
  float Aa[16], wr[16], h[16];
#pragma unroll
  for (int n=0;n<16;n++){ Aa[n] = -__expf(A_log[d*16+n]); h[n]=0.f; }
#pragma unroll
  for (int r=0;r<16;r++) wr[r] = dtw[d*16+r];
  const float bias = dtb[d], Dv = Dskip[d];
  const float* xsp = xs + (size_t)b*8192 + d;
  float* zp = xz + (size_t)b*16384 + d;
#pragma unroll
  for (int l=0;l<16;l++){
    float dt = bias;
#pragma unroll
    for (int r=0;r<16;r++) dt += sdbl[l*48+r]*wr[r];
    const float delta = (dt > 20.f) ? dt : log1pf(__expf(dt));
    const float xl = xsp[(size_t)l*512];
    float yv = 0.f;
#pragma unroll
    for (int n=0;n<16;n++){
      const float dA = __expf(delta*Aa[n]);
      h[n] = dA*h[n] + (delta*sdbl[l*48+16+n])*xl;
      yv += h[n]*sdbl[l*48+32+n];
    }
    yv += Dv*xl;
    const float zl = zp[(size_t)l*1024 + 512];
    yv *= zl*sigf(zl);
    zp[(size_t)l*1024] = yv;                  // y overwrites x-half of xz
  }
}

extern "C" void kernel_launch(void* const* d_in, const int* in_sizes, int n_in,
                              void* d_out, int out_size, void* d_ws, size_t ws_size,
                              hipStream_t stream)
{
  const float* F_clip    = (const float*)d_in[0];
  const float* F_content = (const float*)d_in[1];
  const float* fs_w      = (const float*)d_in[2];
  const float* fs_b      = (const float*)d_in[3];
  const float* in_proj_w = (const float*)d_in[4];
  const float* conv_w    = (const float*)d_in[5];
  const float* conv_b    = (const float*)d_in[6];
  const float* x_proj_w  = (const float*)d_in[7];
  const float* dt_proj_w = (const float*)d_in[8];
  const float* dt_proj_b = (const float*)d_in[9];
  const float* A_log     = (const float*)d_in[10];
  const float* D_skip    = (const float*)d_in[11];
  const float* out_proj_w= (const float*)d_in[12];
  const float* fc1_w     = (const float*)d_in[13];
  const float* fc1_b     = (const float*)d_in[14];
  const float* fc2_w     = (const float*)d_in[15];
  const float* fc2_b     = (const float*)d_in[16];
  float* out = (float*)d_out;

  float* ws = (float*)d_ws;
  float* w_mods = ws;                    // 512*1536            =   786432
  float* w_x0   = w_mods + 786432;       // 8192*256            =  2097152
  float* w_u    = w_x0   + 2097152;      // 8192*256
  float* w_xz   = w_u    + 2097152;      // 8192*1024           =  8388608
  float* w_xs   = w_xz   + 8388608;      // 8192*512            =  4194304
  float* w_dbl  = w_xs   + 4194304;      // 8192*48             =   393216
  float* w_hmid = w_dbl  + 393216;       // 8192*256
  float* w_x1   = w_u;                   // reuse (u dead after K3)
  float* w_u2   = w_x0;                  // reuse (x0 dead after K6)
  // total: 20,054,016 floats = 80.2 MB of d_ws

  // K1: mods = F_clip_s @ fs_w.T + fs_b        (512 x 1536, K=512)
  gemm_atw<64,64,32,4,4,1><<<dim3(24,8),256,0,stream>>>(
      F_clip,512, fs_w,512, fs_b, w_mods,1536, nullptr,nullptr,nullptr);
  // K2: pixel shuffle + LN + modulate(sh_m, sc_m) -> x0, u
  ln_mod<true><<<2048,256,0,stream>>>(F_content, w_mods, 0, w_x0, w_u);
  // K3: xz = u @ in_proj_w.T                   (8192 x 1024, K=256)
  gemm_atw<64,64,32,4,4,0><<<dim3(16,128),256,0,stream>>>(
      w_u,256, in_proj_w,256, nullptr, w_xz,1024, nullptr,nullptr,nullptr);
  // K4: depthwise causal conv + silu -> xs
  conv_silu<<<1024,256,0,stream>>>(w_xz, conv_w, conv_b, w_xs);
  // K4b: dbl = xs @ x_proj_w.T                 (8192 x 48, K=512)
  gemm_atw<64,48,32,4,3,0><<<dim3(1,128),256,0,stream>>>(
      w_xs,512, x_proj_w,512, nullptr, w_dbl,48, nullptr,nullptr,nullptr);
  // K5: selective scan + gate -> y (into xz x-half)
  scan_kernel<<<512,512,0,stream>>>(w_xs, w_xz, w_dbl, dt_proj_w, dt_proj_b,
                                    A_log, D_skip);
  // K6: x1 = x0 + g_m * (y @ out_proj_w.T)     (8192 x 256, K=512)
  gemm_atw<64,64,32,4,4,3><<<dim3(4,128),256,0,stream>>>(
      w_xz,1024, out_proj_w,512, nullptr, w_x1,256, w_x0, w_mods, nullptr);
  // K6b: LN + modulate(sh_p, sc_p) -> u2
  ln_mod<false><<<2048,256,0,stream>>>(w_x1, w_mods, 768, nullptr, w_u2);
  // K7: hmid = gelu(u2 @ fc1_w.T + fc1_b)      (8192 x 256, K=256)
  gemm_atw<64,64,32,4,4,2><<<dim3(4,128),256,0,stream>>>(
      w_u2,256, fc1_w,256, fc1_b, w_hmid,256, nullptr,nullptr,nullptr);
  // K8: out = unshuffle(x1 + g_p*(hmid @ fc2_w.T + fc2_b))
  gemm_atw<64,64,32,4,4,4><<<dim3(4,128),256,0,stream>>>(
      w_hmid,256, fc2_w,256, fc2_b, nullptr,256, w_x1, w_mods, out);
}

// Round 2
// 136.998 us; speedup vs baseline: 2.2703x; 2.2703x over previous
//
#include <hip/hip_runtime.h>
#include <math.h>

typedef unsigned short u16;
typedef unsigned int u32;
typedef __attribute__((ext_vector_type(8))) short bf16x8;
typedef __attribute__((ext_vector_type(4))) float f32x4;

#define AS1 __attribute__((address_space(1)))
#define AS3 __attribute__((address_space(3)))

__device__ __forceinline__ float sigf(float x){ return 1.f/(1.f+__expf(-x)); }
__device__ __forceinline__ float geluf(float x){
  float x3 = x*x*x;
  return 0.5f*x*(1.f + tanhf(0.7978845608f*(x + 0.044715f*x3)));
}
__device__ __forceinline__ float bf2f(u16 u){ return __uint_as_float(((u32)u)<<16); }
__device__ __forceinline__ u16 f2bf(float x){           // round-to-nearest-even
  u32 u = __float_as_uint(x);
  u32 r = (u + 0x7FFFu + ((u>>16)&1u)) >> 16;
  return (u16)r;
}

// ---------------------------------------------------------------------------
// bf16 MFMA GEMM: C[m][n] = sum_k A[m][k] * W[n][k]  (both K-contiguous)
// 128x128 tile, BK=64, 4 waves (2x2), each wave 64x64 = 4x4 fragments of 16x16.
// global_load_lds(16B) staging with XOR-swizzled source <-> swizzled ds_read.
// EPI: 0=store f32 (N-guard), 1=+bias f32, 2=gelu(+bias)->bf16, 5=bf16,
//      3=x0+g_m*acc f32, 4=x1+g_p*(acc+bias) -> inverse pixel-shuffle scatter.
// ---------------------------------------------------------------------------
template<int EPI>
__global__ __launch_bounds__(256) void gemm_mfma(
    const u16* __restrict__ A, int lda,
    const u16* __restrict__ W, int ldw,
    int K, int Nvalid,
    const float* __restrict__ bias,
    void* __restrict__ Cout, int ldc,
    const float* __restrict__ aux0,   // x0 (EPI3) / x1 (EPI4), ld 256, fp32
    const float* __restrict__ mods,   // (512,1536) fp32
    float* __restrict__ out4)         // final output (EPI4)
{
  __shared__ u16 Alds[128*64];
  __shared__ u16 Blds[128*64];
  const int tid  = threadIdx.x;
  const int lane = tid & 63, wid = tid >> 6;
  const int wr = wid >> 1, wc = wid & 1;
  const int m0 = blockIdx.y*128, n0 = blockIdx.x*128;
  const int ln8 = lane >> 3, lk = lane & 7;

  f32x4 acc[4][4];
#pragma unroll
  for (int i=0;i<4;i++)
#pragma unroll
    for (int j=0;j<4;j++) acc[i][j] = (f32x4){0.f,0.f,0.f,0.f};

  for (int k0 = 0; k0 < K; k0 += 64){
#pragma unroll
    for (int j = 0; j < 4; j++){
      const int c   = wid + j*4;          // chunk 0..15, 1KB each (8 rows)
      const int row = c*8 + ln8;
      const int ks  = lk ^ (row & 7);     // inverse-swizzled source k-slot
      {
        const u16* src = A + (size_t)(m0+row)*lda + k0 + 8*ks;
        __builtin_amdgcn_global_load_lds((AS1 const void*)src,
                                         (AS3 void*)&Alds[c*512], 16, 0, 0);
      }
      {
        int rn = n0 + row; if (rn > Nvalid-1) rn = Nvalid-1;
        const u16* src = W + (size_t)rn*ldw + k0 + 8*ks;
        __builtin_amdgcn_global_load_lds((AS1 const void*)src,
                                         (AS3 void*)&Blds[c*512], 16, 0, 0);
      }
    }
    __syncthreads();
#pragma unroll
    for (int kk = 0; kk < 2; kk++){
      bf16x8 af[4], bf[4];
#pragma unroll
      for (int i = 0; i < 4; i++){
        const int row = wr*64 + i*16 + (lane & 15);
        const int col = wc*64 + i*16 + (lane & 15);
        const int ks  = kk*4 + (lane >> 4);
        af[i] = *(const bf16x8*)&Alds[row*64 + 8*(ks ^ (row & 7))];
        bf[i] = *(const bf16x8*)&Blds[col*64 + 8*(ks ^ (col & 7))];
      }
#pragma unroll
      for (int i = 0; i < 4; i++)
#pragma unroll
        for (int j = 0; j < 4; j++)
          acc[i][j] = __builtin_amdgcn_mfma_f32_16x16x32_bf16(af[i], bf[j], acc[i][j], 0, 0, 0);
    }
    __syncthreads();
  }

  // Epilogue. C/D layout: col = lane&15, row = (lane>>4)*4 + r.
#pragma unroll
  for (int j = 0; j < 4; j++){
    const int n = n0 + wc*64 + j*16 + (lane & 15);
    if (n >= Nvalid) continue;
    float bv = 0.f;
    if constexpr (EPI==1 || EPI==2 || EPI==4) bv = bias[n];
#pragma unroll
    for (int i = 0; i < 4; i++){
#pragma unroll
      for (int r = 0; r < 4; r++){
        const int m = m0 + wr*64 + i*16 + (lane>>4)*4 + r;
        const int b = m >> 4;
        float x = acc[i][j][r];
        if constexpr (EPI==0){ ((float*)Cout)[(size_t)m*ldc+n] = x; }
        if constexpr (EPI==1){ ((float*)Cout)[(size_t)m*ldc+n] = x + bv; }
        if constexpr (EPI==2){ ((u16*)Cout)[(size_t)m*ldc+n] = f2bf(geluf(x + bv)); }
        if constexpr (EPI==5){ ((u16*)Cout)[(size_t)m*ldc+n] = f2bf(x); }
        if constexpr (EPI==3){
          ((float*)Cout)[(size_t)m*ldc+n] =
              aux0[(size_t)m*256+n] + mods[(size_t)b*1536+512+n]*x;
        }
        if constexpr (EPI==4){
          float v = aux0[(size_t)m*256+n] + mods[(size_t)b*1536+1280+n]*(x + bv);
          const int pos = m & 15;
          const int c = n>>6, hr=(n>>3)&7, wrr=n&7;
          const int hh = (pos>>2)*8+hr, ww=(pos&3)*8+wrr;
          out4[(((size_t)b*4+c)*32+hh)*32+ww] = v;
        }
      }
    }
  }
}

// fp32 -> bf16 conversion of F_clip + 6 weight matrices, one fused kernel.
// 1560 blocks x 256 threads, 4 elements (1 float4) per thread.
__global__ __launch_bounds__(256) void cvt_bf16(
    const float* __restrict__ clip, const float* __restrict__ fsw,
    const float* __restrict__ inp,  const float* __restrict__ xp,
    const float* __restrict__ outp, const float* __restrict__ f1,
    const float* __restrict__ f2,   u16* __restrict__ dst)
{
  const int q = blockIdx.x*256 + threadIdx.x;   // quad index (x4 elems)
  const float* s; int off;
  if      (q < 65536)  { s = clip; off = q*4; }
  else if (q < 262144) { s = fsw;  off = (q-65536)*4; }
  else if (q < 327680) { s = inp;  off = (q-262144)*4; }
  else if (q < 333824) { s = xp;   off = (q-327680)*4; }
  else if (q < 366592) { s = outp; off = (q-333824)*4; }
  else if (q < 382976) { s = f1;   off = (q-366592)*4; }
  else                 { s = f2;   off = (q-382976)*4; }
  float4 v = *(const float4*)&s[off];
  uint2 o;
  o.x = (u32)f2bf(v.x) | ((u32)f2bf(v.y)<<16);
  o.y = (u32)f2bf(v.z) | ((u32)f2bf(v.w)<<16);
  *(uint2*)&dst[(size_t)q*4] = o;
}

// LayerNorm + modulate. SHUF: gather via pixel shuffle, also write x0 (fp32).
// u output is bf16. One wave per row of 256, 4 rows/block.
template<bool SHUF>
__global__ __launch_bounds__(256) void ln_mod(
    const float* __restrict__ src, const float* __restrict__ mods,
    int sh_off, float* __restrict__ x0_out, u16* __restrict__ u_out)
{
  const int wave = threadIdx.x>>6, lane = threadIdx.x&63;
  const int m = blockIdx.x*4 + wave;
  const int b = m>>4;
  const int c0 = lane*4;
  float4 v;
  if constexpr (SHUF){
    const int pos=m&15, hb=pos>>2, wb=pos&3;
    const int c=c0>>6, hr=(c0>>3)&7, wrb=c0&7;
    v = *(const float4*)&src[(((size_t)b*4+c)*32 + hb*8+hr)*32 + wb*8 + wrb];
  } else {
    v = *(const float4*)&src[(size_t)m*256 + c0];
  }
  float s  = v.x+v.y+v.z+v.w;
  float s2 = v.x*v.x+v.y*v.y+v.z*v.z+v.w*v.w;
#pragma unroll
  for (int off=1; off<64; off<<=1){
    s  += __shfl_xor(s, off);
    s2 += __shfl_xor(s2, off);
  }
  const float mean = s*(1.f/256.f);
  const float var  = s2*(1.f/256.f) - mean*mean;
  const float rs   = rsqrtf(var + 1e-6f);
  float4 sh = *(const float4*)&mods[(size_t)b*1536 + sh_off + c0];
  float4 sc = *(const float4*)&mods[(size_t)b*1536 + sh_off + 256 + c0];
  float ux = (v.x-mean)*rs*(1.f+sc.x) + sh.x;
  float uy = (v.y-mean)*rs*(1.f+sc.y) + sh.y;
  float uz = (v.z-mean)*rs*(1.f+sc.z) + sh.z;
  float uw = (v.w-mean)*rs*(1.f+sc.w) + sh.w;
  if constexpr (SHUF) *(float4*)&x0_out[(size_t)m*256+c0] = v;
  uint2 o;
  o.x = (u32)f2bf(ux) | ((u32)f2bf(uy)<<16);
  o.y = (u32)f2bf(uz) | ((u32)f2bf(uw)<<16);
  *(uint2*)&u_out[(size_t)m*256+c0] = o;
}

// Depthwise causal conv (k=4) + SiLU, bf16 in (x-half of xz) / bf16 out.
__global__ __launch_bounds__(256) void conv_silu(
    const u16* __restrict__ xz, const float* __restrict__ cw,
    const float* __restrict__ cb, u16* __restrict__ xs)
{
  const int t = blockIdx.x*256 + threadIdx.x;
  const int b = t>>9, d = t&511;
  const u16* xp = xz + (size_t)b*16384 + d;
  float x[16];
#pragma unroll
  for (int l=0;l<16;l++) x[l] = bf2f(xp[(size_t)l*1024]);
  const float w0=cw[d*4+0], w1=cw[d*4+1], w2=cw[d*4+2], w3=cw[d*4+3];
  const float bias = cb[d];
  u16* op = xs + (size_t)b*8192 + d;
#pragma unroll
  for (int l=0;l<16;l++){
    float a = bias + w3*x[l];
    if (l>=1) a += w2*x[l-1];
    if (l>=2) a += w1*x[l-2];
    if (l>=3) a += w0*x[l-3];
    a = a*sigf(a);
    op[(size_t)l*512] = f2bf(a);
  }
}

// Selective scan. Block per batch, thread per channel. y -> bf16.
__global__ __launch_bounds__(512) void scan_kernel(
    const u16* __restrict__ xs, const u16* __restrict__ xz,
    u16* __restrict__ y_bf,
    const float* __restrict__ dbl, const float* __restrict__ dtw,
    const float* __restrict__ dtb, const float* __restrict__ A_log,
    const float* __restrict__ Dskip)
{
  const int b = blockIdx.x, d = threadIdx.x;
  __shared__ float sdbl[768];                 // (16, 48): dt | B | C
  for (int i=d;i<768;i+=512) sdbl[i] = dbl[(size_t)b*768 + i];
  __syncthreads();
  float Aa[16], wr[16], h[16];
#pragma unroll
  for (int n=0;n<16;n++){ Aa[n] = -__expf(A_log[d*16+n]); h[n]=0.f; }
#pragma unroll
  for (int r=0;r<16;r++) wr[r] = dtw[d*16+r];
  const float bias = dtb[d], Dv = Dskip[d];
  const u16* xsp = xs + (size_t)b*8192 + d;
  const u16* zp  = xz + (size_t)b*16384 + 512 + d;
  u16* yp = y_bf + (size_t)b*8192 + d;
#pragma unroll
  for (int l=0;l<16;l++){
    float dt = bias;
#pragma unroll
    for (int r=0;r<16;r++) dt += sdbl[l*48+r]*wr[r];
    const float delta = (dt > 20.f) ? dt : log1pf(__expf(dt));
    const float xl = bf2f(xsp[(size_t)l*512]);
    float yv = 0.f;
#pragma unroll
    for (int n=0;n<16;n++){
      const float dA = __expf(delta*Aa[n]);
      h[n] = dA*h[n] + (delta*sdbl[l*48+16+n])*xl;
      yv += h[n]*sdbl[l*48+32+n];
    }
    yv += Dv*xl;
    const float zl = bf2f(zp[(size_t)l*1024]);
    yv *= zl*sigf(zl);
    yp[(size_t)l*512] = f2bf(yv);
  }
}

extern "C" void kernel_launch(void* const* d_in, const int* in_sizes, int n_in,
                              void* d_out, int out_size, void* d_ws, size_t ws_size,
                              hipStream_t stream)
{
  const float* F_clip    = (const float*)d_in[0];
  const float* F_content = (const float*)d_in[1];
  const float* fs_w      = (const float*)d_in[2];
  const float* fs_b      = (const float*)d_in[3];
  const float* conv_w    = (const float*)d_in[5];
  const float* conv_b    = (const float*)d_in[6];
  const float* dt_proj_w = (const float*)d_in[8];
  const float* dt_proj_b = (const float*)d_in[9];
  const float* A_log     = (const float*)d_in[10];
  const float* D_skip    = (const float*)d_in[11];
  const float* fc1_b     = (const float*)d_in[14];
  const float* fc2_b     = (const float*)d_in[16];
  float* out = (float*)d_out;

  float* ws = (float*)d_ws;
  float* w_mods = ws;                    // 786432 f
  float* w_x0   = w_mods + 786432;       // 2097152 f
  float* w_x1   = w_x0   + 2097152;      // 2097152 f
  float* w_dbl  = w_x1   + 2097152;      // 393216 f
  u16* u_bf    = (u16*)(w_dbl + 393216); // 2097152 h
  u16* xz_bf   = u_bf    + 2097152;      // 8388608 h
  u16* xs_bf   = xz_bf   + 8388608;      // 4194304 h
  u16* y_bf    = xs_bf   + 4194304;      // 4194304 h
  u16* u2_bf   = y_bf    + 4194304;      // 2097152 h
  u16* hmid_bf = u2_bf   + 2097152;      // 2097152 h
  u16* wt_bf   = hmid_bf + 2097152;      // 1597440 h   (~71 MB total)

  u16* clip_bf = wt_bf;
  u16* fsw_bf  = wt_bf + 262144;
  u16* inp_bf  = wt_bf + 1048576;
  u16* xp_bf   = wt_bf + 1310720;
  u16* outp_bf = wt_bf + 1335296;
  u16* fc1_bf  = wt_bf + 1466368;
  u16* fc2_bf  = wt_bf + 1531904;

  // K0: fp32 -> bf16 for F_clip + all GEMM weights
  cvt_bf16<<<1560,256,0,stream>>>(F_clip, (const float*)d_in[2],
      (const float*)d_in[4], (const float*)d_in[7], (const float*)d_in[12],
      (const float*)d_in[13], (const float*)d_in[15], wt_bf);
  // K1: mods = F_clip @ fs_w.T + fs_b           (512 x 1536, K=512)
  gemm_mfma<1><<<dim3(12,4),256,0,stream>>>(clip_bf,512, fsw_bf,512, 512,1536,
      fs_b, w_mods,1536, nullptr,nullptr,nullptr);
  // K2: pixel shuffle + LN + modulate -> x0 (f32), u (bf16)
  ln_mod<true><<<2048,256,0,stream>>>(F_content, w_mods, 0, w_x0, u_bf);
  // K3: xz = u @ in_proj.T                      (8192 x 1024, K=256) -> bf16
  gemm_mfma<5><<<dim3(8,64),256,0,stream>>>(u_bf,256, inp_bf,256, 256,1024,
      nullptr, xz_bf,1024, nullptr,nullptr,nullptr);
  // K4: depthwise causal conv + silu -> xs (bf16)
  conv_silu<<<1024,256,0,stream>>>(xz_bf, conv_w, conv_b, xs_bf);
  // K4b: dbl = xs @ x_proj.T                    (8192 x 48, K=512) -> f32
  gemm_mfma<0><<<dim3(1,64),256,0,stream>>>(xs_bf,512, xp_bf,512, 512,48,
      nullptr, w_dbl,48, nullptr,nullptr,nullptr);
  // K5: selective scan + gate -> y (bf16)
  scan_kernel<<<512,512,0,stream>>>(xs_bf, xz_bf, y_bf, w_dbl, dt_proj_w,
                                    dt_proj_b, A_log, D_skip);
  // K6: x1 = x0 + g_m * (y @ out_proj.T)        (8192 x 256, K=512) -> f32
  gemm_mfma<3><<<dim3(2,64),256,0,stream>>>(y_bf,512, outp_bf,512, 512,256,
      nullptr, w_x1,256, w_x0, w_mods, nullptr);
  // K6b: LN + modulate -> u2 (bf16)
  ln_mod<false><<<2048,256,0,stream>>>(w_x1, w_mods, 768, nullptr, u2_bf);
  // K7: hmid = gelu(u2 @ fc1.T + b)             (8192 x 256, K=256) -> bf16
  gemm_mfma<2><<<dim3(2,64),256,0,stream>>>(u2_bf,256, fc1_bf,256, 256,256,
      fc1_b, hmid_bf,256, nullptr,nullptr,nullptr);
  // K8: out = unshuffle(x1 + g_p*(hmid @ fc2.T + b))
  gemm_mfma<4><<<dim3(2,64),256,0,stream>>>(hmid_bf,256, fc2_bf,256, 256,256,
      fc2_b, nullptr,256, w_x1, w_mods, out);
}